// Round 5
// baseline (279.478 us; speedup 1.0000x reference)
//
#include <hip/hip_runtime.h>
#include <hip/hip_bf16.h>

#define D 128
#define SCAN_T 256
#define SCAN_I 4
#define SCAN_CHUNK (SCAN_T * SCAN_I)

typedef __attribute__((ext_vector_type(8))) short short8;
typedef __attribute__((ext_vector_type(4))) float f32x4;

__device__ __forceinline__ unsigned short us_bf16(float f) {
    return __bfloat16_as_ushort(__float2bfloat16(f));
}
__device__ __forceinline__ unsigned pack_bf16(float a, float b) {
    return (unsigned)us_bf16(a) | ((unsigned)us_bf16(b) << 16);
}
__device__ __forceinline__ float bf_lo(unsigned v) { return __uint_as_float(v << 16); }
__device__ __forceinline__ float bf_hi(unsigned v) { return __uint_as_float(v & 0xffff0000u); }

// ---------- fused prep: x->bf16, W->bf16 transposed, degree histogram ----------
__global__ __launch_bounds__(256) void k_prep(const float* __restrict__ x,
                                              unsigned* __restrict__ xb, int nf4,
                                              const float* __restrict__ W1,
                                              const float* __restrict__ W2,
                                              unsigned short* __restrict__ W1t,
                                              unsigned short* __restrict__ W2t,
                                              const int* __restrict__ tgt,
                                              int* __restrict__ deg, int E) {
    int i0 = blockIdx.x * blockDim.x + threadIdx.x;
    int stride = gridDim.x * blockDim.x;
    for (int i = i0; i < nf4; i += stride) {
        float4 v = reinterpret_cast<const float4*>(x)[i];
        uint2 o;
        o.x = pack_bf16(v.x, v.y);
        o.y = pack_bf16(v.z, v.w);
        reinterpret_cast<uint2*>(xb)[i] = o;
    }
    if (i0 < 16384) {
        int k = i0 >> 7, nn = i0 & 127;
        W1t[nn * 128 + k] = us_bf16(W1[i0]);
        W2t[nn * 128 + k] = us_bf16(W2[i0]);
    }
    for (int e = i0; e < E; e += stride) atomicAdd(&deg[tgt[e]], 1);
}

// ---------- CSR scan ----------
__global__ __launch_bounds__(SCAN_T) void k_scan_local(const int* __restrict__ deg,
                                                       int* __restrict__ rowptr,
                                                       int* __restrict__ part, int n) {
    __shared__ int sh[SCAN_T];
    int base = blockIdx.x * SCAN_CHUNK + threadIdx.x * SCAN_I;
    int v[SCAN_I]; int tsum = 0;
    #pragma unroll
    for (int k = 0; k < SCAN_I; ++k) { int idx = base + k; v[k] = (idx < n) ? deg[idx] : 0; tsum += v[k]; }
    sh[threadIdx.x] = tsum; __syncthreads();
    for (int off = 1; off < SCAN_T; off <<= 1) {
        int o = (threadIdx.x >= (unsigned)off) ? sh[threadIdx.x - off] : 0;
        __syncthreads();
        sh[threadIdx.x] += o;
        __syncthreads();
    }
    int excl = sh[threadIdx.x] - tsum;
    #pragma unroll
    for (int k = 0; k < SCAN_I; ++k) { int idx = base + k; if (idx < n) rowptr[idx] = excl; excl += v[k]; }
    if (threadIdx.x == 0) part[blockIdx.x] = sh[SCAN_T - 1];
}

__global__ __launch_bounds__(SCAN_T) void k_scan_mid(int* part, int nblk) {
    __shared__ int sh[SCAN_T];
    int v = (threadIdx.x < (unsigned)nblk) ? part[threadIdx.x] : 0;
    sh[threadIdx.x] = v; __syncthreads();
    for (int off = 1; off < SCAN_T; off <<= 1) {
        int o = (threadIdx.x >= (unsigned)off) ? sh[threadIdx.x - off] : 0;
        __syncthreads();
        sh[threadIdx.x] += o;
        __syncthreads();
    }
    if (threadIdx.x < (unsigned)nblk) part[threadIdx.x] = sh[threadIdx.x] - v;
}

__global__ __launch_bounds__(256) void k_scan_add(int* __restrict__ rowptr,
                                                  int* __restrict__ cursor,
                                                  const int* __restrict__ part, int n, int E) {
    int i = blockIdx.x * blockDim.x + threadIdx.x;
    if (i < n) { int r = rowptr[i] + part[i / SCAN_CHUNK]; rowptr[i] = r; cursor[i] = r; }
    if (i == n) rowptr[n] = E;
}

// XCD-sliced reorder (see round-4 note: slice by target range for L2 write merge)
__global__ __launch_bounds__(256) void k_reorder(const int* __restrict__ src,
                                                 const int* __restrict__ tgt,
                                                 const float* __restrict__ ew,
                                                 int* __restrict__ cursor,
                                                 int2* __restrict__ csr, int E, int sliceN) {
    int slice = blockIdx.x & 7;
    int lo = slice * sliceN, hi = lo + sliceN;
    int tpslice = (gridDim.x >> 3) * blockDim.x;
    int i = (blockIdx.x >> 3) * blockDim.x + threadIdx.x;
    for (int e = i; e < E; e += tpslice) {
        int t = tgt[e];
        if (t >= lo && t < hi) {
            int pos = atomicAdd(&cursor[t], 1);
            csr[pos] = make_int2(src[e], __float_as_int(ew[e]));
        }
    }
}

// ---------- aggregate: 1 wave per node ----------
// Gather layout: lane = eg*16+dg; edge-group eg handles edge it*4+eg, dim-group dg
// handles dims [dg*8, dg*8+8) via one uint4 (16B) load. csr entries broadcast-read
// directly per 16-lane group (no shuffles in the hot loop), prefetched 4 iters deep.
__global__ __launch_bounds__(256) void k_agg(
    const int* __restrict__ rowptr, const int2* __restrict__ csr,
    const uint4* __restrict__ xb4, unsigned* __restrict__ cmb, int n)
{
    int w = threadIdx.x >> 6;
    int lane = threadIdx.x & 63;
    int node = blockIdx.x * 4 + w;
    if (node >= n) node = n - 1;   // benign duplicate on tail

    int r0 = rowptr[node], r1 = rowptr[node + 1];
    int cnt = r1 - r0;

    // softmax stats: lane-per-edge chunked (1 iter for deg<=64; csr stays L1-hot)
    float m = -INFINITY;
    for (int c = r0 + lane; c < r1; c += 64) m = fmaxf(m, __int_as_float(csr[c].y));
    #pragma unroll
    for (int off = 32; off; off >>= 1) m = fmaxf(m, __shfl_xor(m, off));
    float s = 0.f;
    for (int c = r0 + lane; c < r1; c += 64) s += __expf(__int_as_float(csr[c].y) - m);
    #pragma unroll
    for (int off = 32; off; off >>= 1) s += __shfl_xor(s, off);
    float inv = (s > 0.f) ? (1.f / s) : 0.f;

    int eg = lane >> 4;
    int dg = lane & 15;

    float acc[8];
    #pragma unroll
    for (int j = 0; j < 8; ++j) acc[j] = 0.f;

    int clampLast = (cnt > 0) ? cnt - 1 : 0;
    int nit = (cnt + 3) >> 2;   // 4 edges per iteration
    for (int blk = 0; blk < nit; blk += 4) {
        int2 cp[4];
        #pragma unroll
        for (int i = 0; i < 4; ++i) {
            int eidx = (blk + i) * 4 + eg;
            cp[i] = csr[r0 + (eidx < cnt ? eidx : clampLast)];
        }
        #pragma unroll
        for (int i = 0; i < 4; ++i) {
            if ((blk + i) * 4 >= cnt) break;   // wave-uniform cutoff
            int eidx = (blk + i) * 4 + eg;
            float wn = (eidx < cnt) ? __expf(__int_as_float(cp[i].y) - m) * inv : 0.f;
            uint4 v = xb4[cp[i].x * 16 + dg];
            acc[0] = fmaf(wn, bf_lo(v.x), acc[0]); acc[1] = fmaf(wn, bf_hi(v.x), acc[1]);
            acc[2] = fmaf(wn, bf_lo(v.y), acc[2]); acc[3] = fmaf(wn, bf_hi(v.y), acc[3]);
            acc[4] = fmaf(wn, bf_lo(v.z), acc[4]); acc[5] = fmaf(wn, bf_hi(v.z), acc[5]);
            acc[6] = fmaf(wn, bf_lo(v.w), acc[6]); acc[7] = fmaf(wn, bf_hi(v.w), acc[7]);
        }
    }

    // reduce across the 4 edge-groups (butterfly -> every lane holds full sum)
    #pragma unroll
    for (int j = 0; j < 8; ++j) {
        acc[j] += __shfl_xor(acc[j], 16);
        acc[j] += __shfl_xor(acc[j], 32);
    }

    // squared norm across dims
    float ss = 0.f;
    #pragma unroll
    for (int j = 0; j < 8; ++j) ss = fmaf(acc[j], acc[j], ss);
    #pragma unroll
    for (int off = 8; off; off >>= 1) ss += __shfl_xor(ss, off);
    float rn = 1.f / (sqrtf(ss) + 1e-9f);

    if (eg == 0) {
        uint4 xv = xb4[node * 16 + dg];   // residual from bf16 x (output is bf16 anyway)
        uint4 o;
        o.x = pack_bf16(bf_lo(xv.x) + acc[0] * rn, bf_hi(xv.x) + acc[1] * rn);
        o.y = pack_bf16(bf_lo(xv.y) + acc[2] * rn, bf_hi(xv.y) + acc[3] * rn);
        o.z = pack_bf16(bf_lo(xv.z) + acc[4] * rn, bf_hi(xv.z) + acc[5] * rn);
        o.w = pack_bf16(bf_lo(xv.w) + acc[6] * rn, bf_hi(xv.w) + acc[7] * rn);
        reinterpret_cast<uint4*>(cmb)[(size_t)node * 16 + dg] = o;
    }
}

// ---------- MLP + LN via MFMA: 64 nodes per block, 4 waves ----------
__global__ __launch_bounds__(256) void k_mlp(
    const unsigned* __restrict__ cmb,
    const unsigned short* __restrict__ W1t, const unsigned short* __restrict__ W2t,
    const float* __restrict__ b1, const float* __restrict__ b2,
    const float* __restrict__ gamma, const float* __restrict__ beta,
    float* __restrict__ out, int n)
{
    __shared__ __align__(16) unsigned short sA[64][136];
    __shared__ __align__(16) unsigned short sW[128][136];

    int node0 = blockIdx.x * 64;
    int w = threadIdx.x >> 6;
    int lane = threadIdx.x & 63;
    int lr = lane & 15;
    int lg = lane >> 4;
    int mr = w * 16;

    for (int idx = threadIdx.x; idx < 64 * 16; idx += 256) {
        int row = idx >> 4, seg = idx & 15;
        int gr = node0 + row; if (gr >= n) gr = n - 1;
        uint4 v = reinterpret_cast<const uint4*>(cmb)[(size_t)gr * 16 + seg];
        *reinterpret_cast<uint4*>(&sA[row][seg * 8]) = v;
    }
    for (int idx = threadIdx.x; idx < 128 * 16; idx += 256) {
        int row = idx >> 4, seg = idx & 15;
        uint4 v = reinterpret_cast<const uint4*>(W1t)[row * 16 + seg];
        *reinterpret_cast<uint4*>(&sW[row][seg * 8]) = v;
    }
    __syncthreads();

    short8 aF[4];
    #pragma unroll
    for (int kt = 0; kt < 4; ++kt)
        aF[kt] = *reinterpret_cast<const short8*>(&sA[mr + lr][kt * 32 + lg * 8]);

    #pragma unroll
    for (int nt = 0; nt < 8; ++nt) {
        f32x4 c = {0.f, 0.f, 0.f, 0.f};
        #pragma unroll
        for (int kt = 0; kt < 4; ++kt) {
            short8 bF = *reinterpret_cast<const short8*>(&sW[nt * 16 + lr][kt * 32 + lg * 8]);
            c = __builtin_amdgcn_mfma_f32_16x16x32_bf16(aF[kt], bF, c, 0, 0, 0);
        }
        float b1v = b1[nt * 16 + lr];
        #pragma unroll
        for (int reg = 0; reg < 4; ++reg) {
            float h = fmaxf(c[reg] + b1v, 0.f);
            sA[mr + lg * 4 + reg][nt * 16 + lr] = us_bf16(h);
        }
    }
    __syncthreads();

    for (int idx = threadIdx.x; idx < 128 * 16; idx += 256) {
        int row = idx >> 4, seg = idx & 15;
        uint4 v = reinterpret_cast<const uint4*>(W2t)[row * 16 + seg];
        *reinterpret_cast<uint4*>(&sW[row][seg * 8]) = v;
    }
    __syncthreads();

    short8 a2F[4];
    #pragma unroll
    for (int kt = 0; kt < 4; ++kt)
        a2F[kt] = *reinterpret_cast<const short8*>(&sA[mr + lr][kt * 32 + lg * 8]);

    f32x4 c2[8];
    float b2v[8], gv[8], bev[8];
    #pragma unroll
    for (int nt = 0; nt < 8; ++nt) {
        c2[nt] = (f32x4){0.f, 0.f, 0.f, 0.f};
        #pragma unroll
        for (int kt = 0; kt < 4; ++kt) {
            short8 bF = *reinterpret_cast<const short8*>(&sW[nt * 16 + lr][kt * 32 + lg * 8]);
            c2[nt] = __builtin_amdgcn_mfma_f32_16x16x32_bf16(a2F[kt], bF, c2[nt], 0, 0, 0);
        }
        int col = nt * 16 + lr;
        b2v[nt] = b2[col]; gv[nt] = gamma[col]; bev[nt] = beta[col];
    }

    float rs[4] = {0.f, 0.f, 0.f, 0.f}, sq[4] = {0.f, 0.f, 0.f, 0.f};
    #pragma unroll
    for (int nt = 0; nt < 8; ++nt)
        #pragma unroll
        for (int reg = 0; reg < 4; ++reg) {
            float v = c2[nt][reg] + b2v[nt];
            rs[reg] += v; sq[reg] += v * v;
        }
    #pragma unroll
    for (int off = 1; off <= 8; off <<= 1)
        #pragma unroll
        for (int reg = 0; reg < 4; ++reg) {
            rs[reg] += __shfl_xor(rs[reg], off);
            sq[reg] += __shfl_xor(sq[reg], off);
        }
    float mu[4], rstd[4];
    #pragma unroll
    for (int reg = 0; reg < 4; ++reg) {
        mu[reg] = rs[reg] * (1.f / 128.f);
        float var = sq[reg] * (1.f / 128.f) - mu[reg] * mu[reg];
        rstd[reg] = rsqrtf(var + 1e-5f);
    }

    #pragma unroll
    for (int nt = 0; nt < 8; ++nt)
        #pragma unroll
        for (int reg = 0; reg < 4; ++reg) {
            int gr = node0 + mr + lg * 4 + reg;
            if (gr < n) {
                float v = c2[nt][reg] + b2v[nt];
                out[(size_t)gr * 128 + nt * 16 + lr] = gv[nt] * (v - mu[reg]) * rstd[reg] + bev[nt];
            }
        }
}

extern "C" void kernel_launch(void* const* d_in, const int* in_sizes, int n_in,
                              void* d_out, int out_size, void* d_ws, size_t ws_size,
                              hipStream_t stream) {
    const float* x     = (const float*)d_in[0];
    const int*   ei    = (const int*)d_in[1];
    const float* ew    = (const float*)d_in[2];
    const float* W1    = (const float*)d_in[3];
    const float* b1    = (const float*)d_in[4];
    const float* W2    = (const float*)d_in[5];
    const float* b2    = (const float*)d_in[6];
    const float* gamma = (const float*)d_in[7];
    const float* beta  = (const float*)d_in[8];

    int n = in_sizes[0] / D;
    int E = in_sizes[2];
    const int* src = ei;
    const int* tgt = ei + E;

    char* ws = (char*)d_ws;
    int2*     csr    = (int2*)ws;     ws += (size_t)E * sizeof(int2);
    unsigned* xb     = (unsigned*)ws; ws += (size_t)n * 64 * sizeof(unsigned);
    unsigned* cmb    = (unsigned*)ws; ws += (size_t)n * 64 * sizeof(unsigned);
    unsigned short* W1t = (unsigned short*)ws; ws += 128 * 128 * sizeof(unsigned short);
    unsigned short* W2t = (unsigned short*)ws; ws += 128 * 128 * sizeof(unsigned short);
    int*      deg    = (int*)ws;      ws += (size_t)n * sizeof(int);
    int*      rowptr = (int*)ws;      ws += ((size_t)n + 1) * sizeof(int);
    int*      cursor = (int*)ws;      ws += (size_t)n * sizeof(int);
    int*      part   = (int*)ws;      ws += (size_t)SCAN_T * sizeof(int);

    hipMemsetAsync((void*)deg, 0, (size_t)n * sizeof(int), stream);

    int nf4 = n * D / 4;
    k_prep<<<2048, 256, 0, stream>>>(x, xb, nf4, W1, W2, W1t, W2t, tgt, deg, E);

    int nblk = (n + SCAN_CHUNK - 1) / SCAN_CHUNK;
    k_scan_local<<<nblk, SCAN_T, 0, stream>>>(deg, rowptr, part, n);
    k_scan_mid<<<1, SCAN_T, 0, stream>>>(part, nblk);
    k_scan_add<<<(n + 256) / 256, 256, 0, stream>>>(rowptr, cursor, part, n, E);

    int sliceN = (n + 7) / 8;
    k_reorder<<<2048, 256, 0, stream>>>(src, tgt, ew, cursor, csr, E, sliceN);

    k_agg<<<(n + 3) / 4, 256, 0, stream>>>(rowptr, csr,
                                           (const uint4*)xb, cmb, n);

    k_mlp<<<(n + 63) / 64, 256, 0, stream>>>(cmb, W1t, W2t, b1, b2, gamma, beta,
                                             (float*)d_out, n);
}

// Round 6
// 269.613 us; speedup vs baseline: 1.0366x; 1.0366x over previous
//
#include <hip/hip_runtime.h>
#include <hip/hip_bf16.h>

#define D 128
#define SCAN_T 256
#define SCAN_I 4
#define SCAN_CHUNK (SCAN_T * SCAN_I)

typedef __attribute__((ext_vector_type(8))) short short8;
typedef __attribute__((ext_vector_type(4))) float f32x4;
typedef _Float16 half2_t __attribute__((ext_vector_type(2)));

__device__ __forceinline__ unsigned short us_bf16(float f) {
    return __bfloat16_as_ushort(__float2bfloat16(f));
}
__device__ __forceinline__ unsigned pack_bf16(float a, float b) {
    return (unsigned)us_bf16(a) | ((unsigned)us_bf16(b) << 16);
}
__device__ __forceinline__ unsigned pack_f16(float a, float b) {
    unsigned short ua = __builtin_bit_cast(unsigned short, (_Float16)a);
    unsigned short ub = __builtin_bit_cast(unsigned short, (_Float16)b);
    return (unsigned)ua | ((unsigned)ub << 16);
}
__device__ __forceinline__ half2_t as_h2(unsigned u) {
    return __builtin_bit_cast(half2_t, u);
}

// ---------- fused prep: x->f16 pairs, W->bf16 transposed, degree histogram ----------
__global__ __launch_bounds__(256) void k_prep(const float* __restrict__ x,
                                              unsigned* __restrict__ xh, int nf4,
                                              const float* __restrict__ W1,
                                              const float* __restrict__ W2,
                                              unsigned short* __restrict__ W1t,
                                              unsigned short* __restrict__ W2t,
                                              const int* __restrict__ tgt,
                                              int* __restrict__ deg, int E) {
    int i0 = blockIdx.x * blockDim.x + threadIdx.x;
    int stride = gridDim.x * blockDim.x;
    for (int i = i0; i < nf4; i += stride) {
        float4 v = reinterpret_cast<const float4*>(x)[i];
        uint2 o;
        o.x = pack_f16(v.x, v.y);
        o.y = pack_f16(v.z, v.w);
        reinterpret_cast<uint2*>(xh)[i] = o;
    }
    if (i0 < 16384) {
        int k = i0 >> 7, nn = i0 & 127;
        W1t[nn * 128 + k] = us_bf16(W1[i0]);
        W2t[nn * 128 + k] = us_bf16(W2[i0]);
    }
    for (int e = i0; e < E; e += stride) atomicAdd(&deg[tgt[e]], 1);
}

// ---------- CSR scan ----------
__global__ __launch_bounds__(SCAN_T) void k_scan_local(const int* __restrict__ deg,
                                                       int* __restrict__ rowptr,
                                                       int* __restrict__ part, int n) {
    __shared__ int sh[SCAN_T];
    int base = blockIdx.x * SCAN_CHUNK + threadIdx.x * SCAN_I;
    int v[SCAN_I]; int tsum = 0;
    #pragma unroll
    for (int k = 0; k < SCAN_I; ++k) { int idx = base + k; v[k] = (idx < n) ? deg[idx] : 0; tsum += v[k]; }
    sh[threadIdx.x] = tsum; __syncthreads();
    for (int off = 1; off < SCAN_T; off <<= 1) {
        int o = (threadIdx.x >= (unsigned)off) ? sh[threadIdx.x - off] : 0;
        __syncthreads();
        sh[threadIdx.x] += o;
        __syncthreads();
    }
    int excl = sh[threadIdx.x] - tsum;
    #pragma unroll
    for (int k = 0; k < SCAN_I; ++k) { int idx = base + k; if (idx < n) rowptr[idx] = excl; excl += v[k]; }
    if (threadIdx.x == 0) part[blockIdx.x] = sh[SCAN_T - 1];
}

// scan_add now also does the 98-entry part-prefix locally (kills k_scan_mid launch)
__global__ __launch_bounds__(256) void k_scan_add(int* __restrict__ rowptr,
                                                  int* __restrict__ cursor,
                                                  const int* __restrict__ part,
                                                  int nblk, int n, int E) {
    __shared__ int sp[256];
    int t = threadIdx.x;
    int v = (t < nblk) ? part[t] : 0;
    sp[t] = v; __syncthreads();
    for (int off = 1; off < 256; off <<= 1) {
        int o = (t >= off) ? sp[t - off] : 0;
        __syncthreads();
        sp[t] += o;
        __syncthreads();
    }
    int i = blockIdx.x * blockDim.x + t;
    if (i <= n) {
        int c = i / SCAN_CHUNK;
        int add = (c == 0) ? 0 : sp[c - 1];   // exclusive prefix of part
        if (i < n) { int r = rowptr[i] + add; rowptr[i] = r; cursor[i] = r; }
        else rowptr[n] = E;
    }
}

// XCD-sliced reorder with int4-vectorized tgt scan.
__global__ __launch_bounds__(256) void k_reorder(const int* __restrict__ src,
                                                 const int* __restrict__ tgt,
                                                 const float* __restrict__ ew,
                                                 int* __restrict__ cursor,
                                                 int2* __restrict__ csr, int E, int sliceN) {
    int slice = blockIdx.x & 7;
    int lo = slice * sliceN, hi = lo + sliceN;
    int tpslice = (gridDim.x >> 3) * blockDim.x;
    int i = (blockIdx.x >> 3) * blockDim.x + threadIdx.x;
    int E4 = E >> 2;
    const int4* tgt4 = reinterpret_cast<const int4*>(tgt);
    for (int q = i; q < E4; q += tpslice) {
        int4 t4 = tgt4[q];
        int e0 = q * 4;
        #pragma unroll
        for (int k = 0; k < 4; ++k) {
            int t = (k == 0) ? t4.x : (k == 1) ? t4.y : (k == 2) ? t4.z : t4.w;
            if (t >= lo && t < hi) {
                int e = e0 + k;
                int pos = atomicAdd(&cursor[t], 1);
                csr[pos] = make_int2(src[e], __float_as_int(ew[e]));
            }
        }
    }
    // tail (E not multiple of 4)
    for (int e = E4 * 4 + i; e < E; e += tpslice) {
        int t = tgt[e];
        if (t >= lo && t < hi) {
            int pos = atomicAdd(&cursor[t], 1);
            csr[pos] = make_int2(src[e], __float_as_int(ew[e]));
        }
    }
}

// ---------- aggregate: 1 wave per node; f16 packed-math gather ----------
// Lane owns dims {2*lane, 2*lane+1}. Per edge: broadcast packed-f16 weight + src
// via shfl (DS pipe), one 4B row-slice load, one v_pk_fma_f16. 4 h2 accumulators
// keep f16 chains short; combined in f32 before normalize.
__global__ __launch_bounds__(256) void k_agg(
    const int* __restrict__ rowptr, const int2* __restrict__ csr,
    const unsigned* __restrict__ xh, unsigned* __restrict__ cmb, int n)
{
    int w = threadIdx.x >> 6;
    int lane = threadIdx.x & 63;
    int node = blockIdx.x * 4 + w;
    if (node >= n) node = n - 1;   // benign duplicate on tail

    int r0 = rowptr[node], r1 = rowptr[node + 1];

    // softmax max
    float m = -INFINITY;
    for (int c = r0 + lane; c < r1; c += 64) m = fmaxf(m, __int_as_float(csr[c].y));
    #pragma unroll
    for (int off = 32; off; off >>= 1) m = fmaxf(m, __shfl_xor(m, off));
    // softmax denom
    float s = 0.f;
    for (int c = r0 + lane; c < r1; c += 64) s += __expf(__int_as_float(csr[c].y) - m);
    #pragma unroll
    for (int off = 32; off; off >>= 1) s += __shfl_xor(s, off);
    float inv = (s > 0.f) ? (1.f / s) : 0.f;

    half2_t hacc0 = (half2_t)0, hacc1 = (half2_t)0, hacc2 = (half2_t)0, hacc3 = (half2_t)0;

    for (int c = r0; c < r1; c += 64) {
        int e = c + lane;
        int2 cr = (e < r1) ? csr[e] : make_int2(0, 0);
        float wn = (e < r1) ? __expf(__int_as_float(cr.y) - m) * inv : 0.f;
        unsigned short wb = __builtin_bit_cast(unsigned short, (_Float16)wn);
        unsigned wp = (unsigned)wb | ((unsigned)wb << 16);   // half2(wn, wn)
        int cnt = min(64, r1 - c);
        int j = 0;
        for (; j + 8 <= cnt; j += 8) {
            unsigned wk[8]; int sk[8];
            #pragma unroll
            for (int k = 0; k < 8; ++k) {
                wk[k] = __shfl(wp, j + k);
                sk[k] = __shfl(cr.x, j + k);
            }
            unsigned v0 = xh[(size_t)sk[0] * 64 + lane];
            unsigned v1 = xh[(size_t)sk[1] * 64 + lane];
            unsigned v2 = xh[(size_t)sk[2] * 64 + lane];
            unsigned v3 = xh[(size_t)sk[3] * 64 + lane];
            unsigned v4 = xh[(size_t)sk[4] * 64 + lane];
            unsigned v5 = xh[(size_t)sk[5] * 64 + lane];
            unsigned v6 = xh[(size_t)sk[6] * 64 + lane];
            unsigned v7 = xh[(size_t)sk[7] * 64 + lane];
            hacc0 += as_h2(wk[0]) * as_h2(v0);
            hacc1 += as_h2(wk[1]) * as_h2(v1);
            hacc2 += as_h2(wk[2]) * as_h2(v2);
            hacc3 += as_h2(wk[3]) * as_h2(v3);
            hacc0 += as_h2(wk[4]) * as_h2(v4);
            hacc1 += as_h2(wk[5]) * as_h2(v5);
            hacc2 += as_h2(wk[6]) * as_h2(v6);
            hacc3 += as_h2(wk[7]) * as_h2(v7);
        }
        for (; j < cnt; ++j) {
            unsigned wj = __shfl(wp, j);
            int sj = __shfl(cr.x, j);
            unsigned v = xh[(size_t)sj * 64 + lane];
            if ((j & 3) == 0) hacc0 += as_h2(wj) * as_h2(v);
            else if ((j & 3) == 1) hacc1 += as_h2(wj) * as_h2(v);
            else if ((j & 3) == 2) hacc2 += as_h2(wj) * as_h2(v);
            else hacc3 += as_h2(wj) * as_h2(v);
        }
    }

    // combine accumulators in f32
    float ax = (float)hacc0.x + (float)hacc1.x + (float)hacc2.x + (float)hacc3.x;
    float ay = (float)hacc0.y + (float)hacc1.y + (float)hacc2.y + (float)hacc3.y;

    // projective average + combined = x + neigh (residual from f16 x)
    float ss = ax * ax + ay * ay;
    #pragma unroll
    for (int off = 32; off; off >>= 1) ss += __shfl_xor(ss, off);
    float rn = 1.f / (sqrtf(ss) + 1e-9f);
    half2_t hx = as_h2(xh[(size_t)node * 64 + lane]);
    float cx = (float)hx.x + ax * rn;
    float cy = (float)hx.y + ay * rn;
    cmb[(size_t)node * 64 + lane] = pack_bf16(cx, cy);
}

// ---------- MLP + LN via MFMA: 64 nodes per block, 4 waves ----------
__global__ __launch_bounds__(256) void k_mlp(
    const unsigned* __restrict__ cmb,
    const unsigned short* __restrict__ W1t, const unsigned short* __restrict__ W2t,
    const float* __restrict__ b1, const float* __restrict__ b2,
    const float* __restrict__ gamma, const float* __restrict__ beta,
    float* __restrict__ out, int n)
{
    __shared__ __align__(16) unsigned short sA[64][136];
    __shared__ __align__(16) unsigned short sW[128][136];

    int node0 = blockIdx.x * 64;
    int w = threadIdx.x >> 6;
    int lane = threadIdx.x & 63;
    int lr = lane & 15;
    int lg = lane >> 4;
    int mr = w * 16;

    for (int idx = threadIdx.x; idx < 64 * 16; idx += 256) {
        int row = idx >> 4, seg = idx & 15;
        int gr = node0 + row; if (gr >= n) gr = n - 1;
        uint4 v = reinterpret_cast<const uint4*>(cmb)[(size_t)gr * 16 + seg];
        *reinterpret_cast<uint4*>(&sA[row][seg * 8]) = v;
    }
    for (int idx = threadIdx.x; idx < 128 * 16; idx += 256) {
        int row = idx >> 4, seg = idx & 15;
        uint4 v = reinterpret_cast<const uint4*>(W1t)[row * 16 + seg];
        *reinterpret_cast<uint4*>(&sW[row][seg * 8]) = v;
    }
    __syncthreads();

    short8 aF[4];
    #pragma unroll
    for (int kt = 0; kt < 4; ++kt)
        aF[kt] = *reinterpret_cast<const short8*>(&sA[mr + lr][kt * 32 + lg * 8]);

    #pragma unroll
    for (int nt = 0; nt < 8; ++nt) {
        f32x4 c = {0.f, 0.f, 0.f, 0.f};
        #pragma unroll
        for (int kt = 0; kt < 4; ++kt) {
            short8 bF = *reinterpret_cast<const short8*>(&sW[nt * 16 + lr][kt * 32 + lg * 8]);
            c = __builtin_amdgcn_mfma_f32_16x16x32_bf16(aF[kt], bF, c, 0, 0, 0);
        }
        float b1v = b1[nt * 16 + lr];
        #pragma unroll
        for (int reg = 0; reg < 4; ++reg) {
            float h = fmaxf(c[reg] + b1v, 0.f);
            sA[mr + lg * 4 + reg][nt * 16 + lr] = us_bf16(h);
        }
    }
    __syncthreads();

    for (int idx = threadIdx.x; idx < 128 * 16; idx += 256) {
        int row = idx >> 4, seg = idx & 15;
        uint4 v = reinterpret_cast<const uint4*>(W2t)[row * 16 + seg];
        *reinterpret_cast<uint4*>(&sW[row][seg * 8]) = v;
    }
    __syncthreads();

    short8 a2F[4];
    #pragma unroll
    for (int kt = 0; kt < 4; ++kt)
        a2F[kt] = *reinterpret_cast<const short8*>(&sA[mr + lr][kt * 32 + lg * 8]);

    f32x4 c2[8];
    float b2v[8], gv[8], bev[8];
    #pragma unroll
    for (int nt = 0; nt < 8; ++nt) {
        c2[nt] = (f32x4){0.f, 0.f, 0.f, 0.f};
        #pragma unroll
        for (int kt = 0; kt < 4; ++kt) {
            short8 bF = *reinterpret_cast<const short8*>(&sW[nt * 16 + lr][kt * 32 + lg * 8]);
            c2[nt] = __builtin_amdgcn_mfma_f32_16x16x32_bf16(a2F[kt], bF, c2[nt], 0, 0, 0);
        }
        int col = nt * 16 + lr;
        b2v[nt] = b2[col]; gv[nt] = gamma[col]; bev[nt] = beta[col];
    }

    float rs[4] = {0.f, 0.f, 0.f, 0.f}, sq[4] = {0.f, 0.f, 0.f, 0.f};
    #pragma unroll
    for (int nt = 0; nt < 8; ++nt)
        #pragma unroll
        for (int reg = 0; reg < 4; ++reg) {
            float v = c2[nt][reg] + b2v[nt];
            rs[reg] += v; sq[reg] += v * v;
        }
    #pragma unroll
    for (int off = 1; off <= 8; off <<= 1)
        #pragma unroll
        for (int reg = 0; reg < 4; ++reg) {
            rs[reg] += __shfl_xor(rs[reg], off);
            sq[reg] += __shfl_xor(sq[reg], off);
        }
    float mu[4], rstd[4];
    #pragma unroll
    for (int reg = 0; reg < 4; ++reg) {
        mu[reg] = rs[reg] * (1.f / 128.f);
        float var = sq[reg] * (1.f / 128.f) - mu[reg] * mu[reg];
        rstd[reg] = rsqrtf(var + 1e-5f);
    }

    #pragma unroll
    for (int nt = 0; nt < 8; ++nt)
        #pragma unroll
        for (int reg = 0; reg < 4; ++reg) {
            int gr = node0 + mr + lg * 4 + reg;
            if (gr < n) {
                float v = c2[nt][reg] + b2v[nt];
                out[(size_t)gr * 128 + nt * 16 + lr] = gv[nt] * (v - mu[reg]) * rstd[reg] + bev[nt];
            }
        }
}

extern "C" void kernel_launch(void* const* d_in, const int* in_sizes, int n_in,
                              void* d_out, int out_size, void* d_ws, size_t ws_size,
                              hipStream_t stream) {
    const float* x     = (const float*)d_in[0];
    const int*   ei    = (const int*)d_in[1];
    const float* ew    = (const float*)d_in[2];
    const float* W1    = (const float*)d_in[3];
    const float* b1    = (const float*)d_in[4];
    const float* W2    = (const float*)d_in[5];
    const float* b2    = (const float*)d_in[6];
    const float* gamma = (const float*)d_in[7];
    const float* beta  = (const float*)d_in[8];

    int n = in_sizes[0] / D;
    int E = in_sizes[2];
    const int* src = ei;
    const int* tgt = ei + E;

    char* ws = (char*)d_ws;
    int2*     csr    = (int2*)ws;     ws += (size_t)E * sizeof(int2);
    unsigned* xh     = (unsigned*)ws; ws += (size_t)n * 64 * sizeof(unsigned);
    unsigned* cmb    = (unsigned*)ws; ws += (size_t)n * 64 * sizeof(unsigned);
    unsigned short* W1t = (unsigned short*)ws; ws += 128 * 128 * sizeof(unsigned short);
    unsigned short* W2t = (unsigned short*)ws; ws += 128 * 128 * sizeof(unsigned short);
    int*      deg    = (int*)ws;      ws += (size_t)n * sizeof(int);
    int*      rowptr = (int*)ws;      ws += ((size_t)n + 1) * sizeof(int);
    int*      cursor = (int*)ws;      ws += (size_t)n * sizeof(int);
    int*      part   = (int*)ws;      ws += (size_t)SCAN_T * sizeof(int);

    hipMemsetAsync((void*)deg, 0, (size_t)n * sizeof(int), stream);

    int nf4 = n * D / 4;
    k_prep<<<2048, 256, 0, stream>>>(x, xh, nf4, W1, W2, W1t, W2t, tgt, deg, E);

    int nblk = (n + SCAN_CHUNK - 1) / SCAN_CHUNK;   // 98 (<=256)
    k_scan_local<<<nblk, SCAN_T, 0, stream>>>(deg, rowptr, part, n);
    k_scan_add<<<(n + 256) / 256, 256, 0, stream>>>(rowptr, cursor, part, nblk, n, E);

    int sliceN = (n + 7) / 8;
    k_reorder<<<2048, 256, 0, stream>>>(src, tgt, ew, cursor, csr, E, sliceN);

    k_agg<<<(n + 3) / 4, 256, 0, stream>>>(rowptr, csr, xh, cmb, n);

    k_mlp<<<(n + 63) / 64, 256, 0, stream>>>(cmb, W1t, W2t, b1, b2, gamma, beta,
                                             (float*)d_out, n);
}